// Round 5
// baseline (79.514 us; speedup 1.0000x reference)
//
#include <hip/hip_runtime.h>

typedef _Float16 f16;
typedef f16 f16x8 __attribute__((ext_vector_type(8)));
typedef f16 f16x4 __attribute__((ext_vector_type(4)));
typedef float f32x4 __attribute__((ext_vector_type(4)));

constexpr float ATT_SCALE = 0.17677669529663687f; // 1/sqrt(32)

// ---------------- DPP wave-64 reductions (no LDS, no ds_bpermute) ----------------
template<int C> __device__ __forceinline__ float dppadd(float v) {
    return v + __int_as_float(__builtin_amdgcn_update_dpp(0, __float_as_int(v), C, 0xf, 0xf, true));
}
template<int C> __device__ __forceinline__ float dppmax(float v) {
    return fmaxf(v, __int_as_float(__builtin_amdgcn_update_dpp(__float_as_int(v), __float_as_int(v), C, 0xf, 0xf, false)));
}
template<int C> __device__ __forceinline__ float dppmin(float v) {
    return fminf(v, __int_as_float(__builtin_amdgcn_update_dpp(__float_as_int(v), __float_as_int(v), C, 0xf, 0xf, false)));
}
__device__ __forceinline__ float wave_sum(float v) {
    v = dppadd<0x111>(v); v = dppadd<0x112>(v); v = dppadd<0x114>(v); v = dppadd<0x118>(v);
    v = dppadd<0x142>(v); v = dppadd<0x143>(v);
    return __int_as_float(__builtin_amdgcn_readlane(__float_as_int(v), 63));
}
__device__ __forceinline__ float wave_max(float v) {
    v = dppmax<0x111>(v); v = dppmax<0x112>(v); v = dppmax<0x114>(v); v = dppmax<0x118>(v);
    v = dppmax<0x142>(v); v = dppmax<0x143>(v);
    return __int_as_float(__builtin_amdgcn_readlane(__float_as_int(v), 63));
}
__device__ __forceinline__ float wave_min(float v) {
    v = dppmin<0x111>(v); v = dppmin<0x112>(v); v = dppmin<0x114>(v); v = dppmin<0x118>(v);
    v = dppmin<0x142>(v); v = dppmin<0x143>(v);
    return __int_as_float(__builtin_amdgcn_readlane(__float_as_int(v), 63));
}

// ------- merged prep: avg-pool (bid<512) | x transpose (bid<1024) | weight cast -------
__global__ __launch_bounds__(256) void prep_kernel(const float* __restrict__ y,
                                                   float* __restrict__ pooled,
                                                   const float* __restrict__ x,
                                                   f16* __restrict__ xT,
                                                   const float* __restrict__ Wq,
                                                   const float* __restrict__ Wkv,
                                                   const float* __restrict__ Wp,
                                                   f16* __restrict__ wq16,
                                                   f16* __restrict__ wkv16,
                                                   f16* __restrict__ wp16)
{
    __shared__ float sh[1444];
    int bid = blockIdx.x, t = threadIdx.x;
    if (bid < 512) {
        float (*p)[38] = (float(*)[38])sh;
        const float* plane = y + (size_t)bid * 1024;
        for (int i = t; i < 38 * 38; i += 256) (&p[0][0])[i] = 0.f;
        __syncthreads();
        for (int i = t; i < 1024; i += 256) p[(i >> 5) + 3][(i & 31) + 3] = plane[i];
        __syncthreads();
        int b = bid >> 8, c = bid & 255;
        for (int i = t; i < 1024; i += 256) {
            int r = (i >> 5) + 3, cc = (i & 31) + 3;
            float s3 = 0.f;
            #pragma unroll
            for (int dr = -1; dr <= 1; ++dr)
                #pragma unroll
                for (int dc = -1; dc <= 1; ++dc) s3 += p[r + dr][cc + dc];
            float r5 = 0.f;
            #pragma unroll
            for (int dc = -2; dc <= 2; ++dc) r5 += p[r - 2][cc + dc] + p[r + 2][cc + dc];
            #pragma unroll
            for (int dr = -1; dr <= 1; ++dr) r5 += p[r + dr][cc - 2] + p[r + dr][cc + 2];
            float r7 = 0.f;
            #pragma unroll
            for (int dc = -3; dc <= 3; ++dc) r7 += p[r - 3][cc + dc] + p[r + 3][cc + dc];
            #pragma unroll
            for (int dr = -2; dr <= 2; ++dr) r7 += p[r + dr][cc - 3] + p[r + dr][cc + 3];
            float s5 = s3 + r5, s7 = s5 + r7;
            // transposed write: pooled[b][n][c]
            pooled[((size_t)b * 1024 + i) * 256 + c] =
                s3 * (1.f / 9.f) + s5 * (1.f / 25.f) + s7 * (1.f / 49.f);
        }
    } else if (bid < 1024) {
        float (*tile)[33] = (float(*)[33])sh;
        int id = bid - 512;
        int b = id >> 8, ct = (id >> 5) & 7, nt = id & 31;
        int rr = t >> 5, j = t & 31;
        #pragma unroll
        for (int r = rr; r < 32; r += 8)
            tile[r][j] = x[((size_t)b * 256 + ct * 32 + r) * 1024 + nt * 32 + j];
        __syncthreads();
        #pragma unroll
        for (int r = rr; r < 32; r += 8)
            xT[((size_t)b * 1024 + nt * 32 + r) * 256 + ct * 32 + j] = (f16)tile[j][r];
    } else {
        int i = (bid - 1024) * 256 + t;
        if (i < 65536) { wq16[i] = (f16)Wq[i]; wp16[i] = (f16)Wp[i]; }
        wkv16[i] = (f16)Wkv[i];
    }
}

// ---------------- merged Q and KV projections (KV with fused LayerNorm) ----------------
__device__ __forceinline__ void gemm_tile(const f16* __restrict__ A, const f16* __restrict__ Bm,
                                          int row0, int ncol0, int l15, int lhi, f32x4 acc[4])
{
    for (int k0 = 0; k0 < 256; k0 += 32) {
        f16x8 a = *(const f16x8*)(A + (size_t)(row0 + l15) * 256 + k0 + lhi * 8);
        #pragma unroll
        for (int j = 0; j < 4; ++j) {
            f16x8 bf = *(const f16x8*)(Bm + (size_t)(ncol0 + j * 16 + l15) * 256 + k0 + lhi * 8);
            acc[j] = __builtin_amdgcn_mfma_f32_16x16x32_f16(a, bf, acc[j], 0, 0, 0);
        }
    }
}

__global__ __launch_bounds__(256) void qkv_kernel(const f16* __restrict__ xT,
                                                  const float* __restrict__ pooled,
                                                  const float* __restrict__ lng,
                                                  const float* __restrict__ lnb,
                                                  const f16* __restrict__ wq16,
                                                  const f16* __restrict__ wkv16,
                                                  f16* __restrict__ q16,
                                                  f16* __restrict__ k16,
                                                  f16* __restrict__ vT16)
{
    __shared__ f16 At[64 * 256];     // 32 KB swizzled A-tile (KV path only)
    int w = threadIdx.x >> 6, lane = threadIdx.x & 63;
    int l15 = lane & 15, lhi = lane >> 4;
    if (blockIdx.x < 128) {
        int mt = blockIdx.x >> 2, nt = blockIdx.x & 3;
        int row0 = mt * 64 + w * 16;
        f32x4 acc[4] = {};
        gemm_tile(xT, wq16, row0, nt * 64, l15, lhi, acc);
        #pragma unroll
        for (int j = 0; j < 4; ++j) {
            int col = nt * 64 + j * 16 + l15;
            int h = col >> 5, d = col & 31;
            #pragma unroll
            for (int r = 0; r < 4; ++r) {
                int row = row0 + 4 * lhi + r;
                int b = row >> 10, n = row & 1023;
                q16[(((size_t)(b * 8 + h)) * 1024 + n) * 32 + d] = (f16)(acc[j][r] * ATT_SCALE);
            }
        }
    } else {
        int bid = blockIdx.x - 128;
        int mt = bid >> 3, nt = bid & 7;
        int row0g = mt * 64;
        // fused LN: wave w normalizes rows [w*16, w*16+16) into swizzled LDS
        float4 gg = ((const float4*)lng)[lane];
        float4 bb = ((const float4*)lnb)[lane];
        for (int rr = 0; rr < 16; ++rr) {
            int r = w * 16 + rr;
            float4 v = *(const float4*)(pooled + (size_t)(row0g + r) * 256 + lane * 4);
            float su = v.x + v.y + v.z + v.w;
            float s2 = v.x * v.x + v.y * v.y + v.z * v.z + v.w * v.w;
            su = wave_sum(su); s2 = wave_sum(s2);
            float muv = su * (1.f / 256.f);
            float rstd = rsqrtf(s2 * (1.f / 256.f) - muv * muv + 1e-5f);
            f16x4 o;
            o[0] = (f16)((v.x - muv) * rstd * gg.x + bb.x);
            o[1] = (f16)((v.y - muv) * rstd * gg.y + bb.y);
            o[2] = (f16)((v.z - muv) * rstd * gg.z + bb.z);
            o[3] = (f16)((v.w - muv) * rstd * gg.w + bb.w);
            *(f16x4*)(At + r * 256 + ((lane * 4) ^ ((r & 7) << 3))) = o;
        }
        __syncthreads();
        // GEMM from LDS A-tile
        f32x4 acc[4] = {};
        int a_r = w * 16 + l15;
        int asw = (a_r & 7) << 3;
        for (int k0 = 0; k0 < 256; k0 += 32) {
            f16x8 a = *(const f16x8*)(At + a_r * 256 + ((k0 + lhi * 8) ^ asw));
            #pragma unroll
            for (int j = 0; j < 4; ++j) {
                f16x8 bf = *(const f16x8*)(wkv16 + (size_t)(nt * 64 + j * 16 + l15) * 256 + k0 + lhi * 8);
                acc[j] = __builtin_amdgcn_mfma_f32_16x16x32_f16(a, bf, acc[j], 0, 0, 0);
            }
        }
        #pragma unroll
        for (int j = 0; j < 4; ++j) {
            int col = nt * 64 + j * 16 + l15;
            #pragma unroll
            for (int r = 0; r < 4; ++r) {
                int row = row0g + w * 16 + 4 * lhi + r;
                int b = row >> 10, n = row & 1023;
                float v = acc[j][r];
                if (col < 256) {
                    int h = col >> 5, d = col & 31;
                    k16[(((size_t)(b * 8 + h)) * 1024 + n) * 32 + d] = (f16)v;
                } else {
                    int c2 = col - 256, h = c2 >> 5, d = c2 & 31;
                    vT16[(((size_t)(b * 8 + h)) * 32 + d) * 1024 + n] = (f16)v;
                }
            }
        }
    }
}

// -------- fused attention v5: swapped QK^T, Gaussian-init dual regula-falsi top-k -----
__global__ __launch_bounds__(1024, 8) void attn_kernel(const f16* __restrict__ q16,
                                                       const f16* __restrict__ k16,
                                                       const f16* __restrict__ vT16,
                                                       const float* __restrict__ a1p,
                                                       const float* __restrict__ a2p,
                                                       f16* __restrict__ oat)
{
    __shared__ float Sb[16 * 1024];      // 64 KB, col-swizzled
    int bid = blockIdx.x;
    int bh = bid >> 6, rb = bid & 63;
    int row0 = rb * 16;
    int w = threadIdx.x >> 6, lane = threadIdx.x & 63;   // w in [0,16)
    int l15 = lane & 15, lhi = lane >> 4;
    const f16* Qb = q16 + (size_t)bh * 32768;
    const f16* Kb = k16 + (size_t)bh * 32768;
    const f16* Vb = vT16 + (size_t)bh * 32768;

    // phase 1: S = Q K^T via mfma(K, Q): lane holds S[q=l15][k=c0+4*lhi+r] -> b128 writes
    {
        f16x8 qf = *(const f16x8*)(Qb + (size_t)(row0 + l15) * 32 + lhi * 8);
        int q = l15, sw1 = (q & 7) << 2;
        #pragma unroll
        for (int j = 0; j < 4; ++j) {
            int c0 = w * 64 + j * 16;
            f16x8 kf = *(const f16x8*)(Kb + (size_t)(c0 + l15) * 32 + lhi * 8);
            f32x4 z = {0.f, 0.f, 0.f, 0.f};
            f32x4 d = __builtin_amdgcn_mfma_f32_16x16x32_f16(kf, qf, z, 0, 0, 0);
            int k0 = c0 + 4 * lhi;
            *(float4*)&Sb[q * 1024 + (k0 ^ sw1)] = *(float4*)&d;
        }
    }
    __syncthreads();

    // phase 2: wave w owns row w
    float c_a1 = a1p[0], c_a2 = a2p[0];
    int r = w, sw = (r & 7) << 2;
    float s[16];
    #pragma unroll
    for (int i = 0; i < 4; ++i) {
        float4 v4 = *(const float4*)&Sb[r * 1024 + ((256 * i + 4 * lane) ^ sw)];
        s[4 * i + 0] = v4.x; s[4 * i + 1] = v4.y; s[4 * i + 2] = v4.z; s[4 * i + 3] = v4.w;
    }
    float mxl = s[0], mnl = s[0], sul = 0.f, s2l = 0.f;
    #pragma unroll
    for (int i = 0; i < 16; ++i) {
        mxl = fmaxf(mxl, s[i]); mnl = fminf(mnl, s[i]);
        sul += s[i]; s2l += s[i] * s[i];
    }
    float mx = wave_max(mxl), mn = wave_min(mnl);
    float mu = wave_sum(sul) * (1.f / 1024.f);
    float s2m = wave_sum(s2l) * (1.f / 1024.f);
    float sg = sqrtf(fmaxf(s2m - mu * mu, 1e-30f));

    // Gaussian-init narrow brackets, then dual regula-falsi to exact count
    float a1 = mu - 0.20f * sg, b1 = mu + 0.20f * sg;
    float g2 = mu + 0.4316f * sg;
    float a2 = g2 - 0.20f * sg, b2 = g2 + 0.20f * sg;
    int ca1 = 0, cb1 = 0, ca2 = 0, cb2 = 0;
    #pragma unroll
    for (int i = 0; i < 16; ++i) {
        ca1 += (int)__popcll(__ballot(s[i] >= a1));
        cb1 += (int)__popcll(__ballot(s[i] >= b1));
        ca2 += (int)__popcll(__ballot(s[i] >= a2));
        cb2 += (int)__popcll(__ballot(s[i] >= b2));
    }
    bool f1 = false, f2 = false;
    float lo1, hi1 = mx, cl1 = 1024.f, ch1 = 1.f;
    float lo2, hi2 = mx, cl2 = 1024.f, ch2 = 1.f;
    if (ca1 == 512)      { f1 = true; lo1 = a1; }
    else if (cb1 == 512) { f1 = true; lo1 = b1; }
    else if (ca1 < 512)  { lo1 = mn; cl1 = 1024.f; hi1 = a1; ch1 = (float)ca1; }
    else if (cb1 >= 512) { lo1 = b1; cl1 = (float)cb1; hi1 = mx; ch1 = 1.f; }
    else                 { lo1 = a1; cl1 = (float)ca1; hi1 = b1; ch1 = (float)cb1; }
    if (ca2 == 341)      { f2 = true; lo2 = a2; }
    else if (cb2 == 341) { f2 = true; lo2 = b2; }
    else if (ca2 < 341)  { lo2 = mn; cl2 = 1024.f; hi2 = a2; ch2 = (float)ca2; }
    else if (cb2 >= 341) { lo2 = b2; cl2 = (float)cb2; hi2 = mx; ch2 = 1.f; }
    else                 { lo2 = a2; cl2 = (float)ca2; hi2 = b2; ch2 = (float)cb2; }

    for (int it = 0; it < 20; ++it) {
        if (f1 && f2) break;
        bool t1 = !f1, t2 = !f2;
        float m1 = lo1, m2 = lo2;
        if (t1) {
            m1 = ((it % 3) == 2) ? (0.5f * (lo1 + hi1))
                                 : (lo1 + (hi1 - lo1) * (cl1 - 512.f) / (cl1 - ch1));
            if (!(m1 > lo1 && m1 < hi1)) m1 = 0.5f * (lo1 + hi1);
            if (!(m1 > lo1 && m1 < hi1)) { f1 = true; t1 = false; }
        }
        if (t2) {
            m2 = ((it % 3) == 2) ? (0.5f * (lo2 + hi2))
                                 : (lo2 + (hi2 - lo2) * (cl2 - 341.f) / (cl2 - ch2));
            if (!(m2 > lo2 && m2 < hi2)) m2 = 0.5f * (lo2 + hi2);
            if (!(m2 > lo2 && m2 < hi2)) { f2 = true; t2 = false; }
        }
        if (!t1 && !t2) continue;
        int c1 = 0, c2 = 0;
        if (t1) {
            #pragma unroll
            for (int i = 0; i < 16; ++i) c1 += (int)__popcll(__ballot(s[i] >= m1));
        }
        if (t2) {
            #pragma unroll
            for (int i = 0; i < 16; ++i) c2 += (int)__popcll(__ballot(s[i] >= m2));
        }
        if (t1) {
            if (c1 == 512) { f1 = true; lo1 = m1; }
            else if (c1 > 512) { lo1 = m1; cl1 = (float)c1; }
            else { hi1 = m1; ch1 = (float)c1; }
        }
        if (t2) {
            if (c2 == 341) { f2 = true; lo2 = m2; }
            else if (c2 > 341) { lo2 = m2; cl2 = (float)c2; }
            else { hi2 = m2; ch2 = (float)c2; }
        }
    }
    float T1 = lo1, T2 = lo2;   // exact-count pivot (fallback: count(lo) >= k)

    float l1 = 0.f, l2 = 0.f;
    #pragma unroll
    for (int i = 0; i < 16; ++i) {
        float ev = __expf(s[i] - mx);
        l1 += (s[i] >= T1) ? ev : 0.f;
        l2 += (s[i] >= T2) ? ev : 0.f;
    }
    l1 = wave_sum(l1); l2 = wave_sum(l2);
    float c1w = c_a1 / l1, c2w = c_a2 / l2;
    #pragma unroll
    for (int i = 0; i < 4; ++i) {
        float4 o4;
        float ev, wt;
        ev = __expf(s[4*i+0] - mx);
        wt = (s[4*i+0] >= T1 ? c1w : 0.f) + (s[4*i+0] >= T2 ? c2w : 0.f); o4.x = ev * wt;
        ev = __expf(s[4*i+1] - mx);
        wt = (s[4*i+1] >= T1 ? c1w : 0.f) + (s[4*i+1] >= T2 ? c2w : 0.f); o4.y = ev * wt;
        ev = __expf(s[4*i+2] - mx);
        wt = (s[4*i+2] >= T1 ? c1w : 0.f) + (s[4*i+2] >= T2 ? c2w : 0.f); o4.z = ev * wt;
        ev = __expf(s[4*i+3] - mx);
        wt = (s[4*i+3] >= T1 ? c1w : 0.f) + (s[4*i+3] >= T2 ? c2w : 0.f); o4.w = ev * wt;
        *(float4*)&Sb[r * 1024 + ((256 * i + 4 * lane) ^ sw)] = o4;
    }
    __syncthreads();

    // phase 3: out = W V, m-range split across 16 waves (64 m each)
    f32x4 acc0 = {}, acc1 = {};
    int swl = (l15 & 7) << 2;
    #pragma unroll
    for (int ks = 0; ks < 2; ++ks) {
        int m0 = w * 64 + ks * 32 + lhi * 8;
        float4 ch0 = *(const float4*)&Sb[l15 * 1024 + ((m0)     ^ swl)];
        float4 ch1 = *(const float4*)&Sb[l15 * 1024 + ((m0 + 4) ^ swl)];
        f16x8 af;
        af[0] = (f16)ch0.x; af[1] = (f16)ch0.y; af[2] = (f16)ch0.z; af[3] = (f16)ch0.w;
        af[4] = (f16)ch1.x; af[5] = (f16)ch1.y; af[6] = (f16)ch1.z; af[7] = (f16)ch1.w;
        f16x8 b0 = *(const f16x8*)(Vb + (size_t)(l15) * 1024 + m0);
        f16x8 b1v = *(const f16x8*)(Vb + (size_t)(16 + l15) * 1024 + m0);
        acc0 = __builtin_amdgcn_mfma_f32_16x16x32_f16(af, b0, acc0, 0, 0, 0);
        acc1 = __builtin_amdgcn_mfma_f32_16x16x32_f16(af, b1v, acc1, 0, 0, 0);
    }
    __syncthreads();
    #pragma unroll
    for (int rr2 = 0; rr2 < 4; ++rr2) {
        int rw = 4 * lhi + rr2;
        Sb[w * 512 + rw * 32 + l15]      = acc0[rr2];
        Sb[w * 512 + rw * 32 + 16 + l15] = acc1[rr2];
    }
    __syncthreads();
    // vectorized 16-way reduce: 128 threads, float4 each
    if (threadIdx.x < 128) {
        int o4 = threadIdx.x << 2;             // element base, 0..508
        float4 v = *(const float4*)&Sb[o4];
        #pragma unroll
        for (int ww = 1; ww < 16; ++ww) {
            float4 p = *(const float4*)&Sb[ww * 512 + o4];
            v.x += p.x; v.y += p.y; v.z += p.z; v.w += p.w;
        }
        int rr = o4 >> 5, d0 = o4 & 31;
        int b = bh >> 3, h = bh & 7;
        f16x4 o;
        o[0] = (f16)v.x; o[1] = (f16)v.y; o[2] = (f16)v.z; o[3] = (f16)v.w;
        *(f16x4*)(oat + ((size_t)b * 1024 + row0 + rr) * 256 + h * 32 + d0) = o;
    }
}

// ---------------- output projection + bias, LDS-transposed coalesced writes ---------
__global__ __launch_bounds__(256) void projgemm_kernel(const f16* __restrict__ A,
                                                       const f16* __restrict__ Bm,
                                                       const float* __restrict__ bias,
                                                       float* __restrict__ out)
{
    __shared__ float tile[64][65];
    int mt = blockIdx.x >> 2, nt = blockIdx.x & 3;
    int w = threadIdx.x >> 6, lane = threadIdx.x & 63;
    int l15 = lane & 15, lhi = lane >> 4;
    int row0 = mt * 64 + w * 16;
    f32x4 acc[4] = {};
    gemm_tile(A, Bm, row0, nt * 64, l15, lhi, acc);
    #pragma unroll
    for (int j = 0; j < 4; ++j) {
        int col_l = j * 16 + l15;
        float bv = bias[nt * 64 + col_l];
        #pragma unroll
        for (int r = 0; r < 4; ++r)
            tile[col_l][w * 16 + 4 * lhi + r] = acc[j][r] + bv;
    }
    __syncthreads();
    int b = (mt * 64) >> 10, n0 = (mt * 64) & 1023;
    int col_l = threadIdx.x >> 2, part = threadIdx.x & 3;
    size_t base = (size_t)b * 262144 + (size_t)(nt * 64 + col_l) * 1024 + n0 + part * 16;
    #pragma unroll
    for (int q = 0; q < 4; ++q) {
        float4 v;
        v.x = tile[col_l][part * 16 + q * 4 + 0];
        v.y = tile[col_l][part * 16 + q * 4 + 1];
        v.z = tile[col_l][part * 16 + q * 4 + 2];
        v.w = tile[col_l][part * 16 + q * 4 + 3];
        *(float4*)(out + base + q * 4) = v;
    }
}

extern "C" void kernel_launch(void* const* d_in, const int* in_sizes, int n_in,
                              void* d_out, int out_size, void* d_ws, size_t ws_size,
                              hipStream_t stream)
{
    const float* x     = (const float*)d_in[0];
    const float* y     = (const float*)d_in[1];
    const float* Wq    = (const float*)d_in[2];
    const float* Wkv   = (const float*)d_in[3];
    const float* Wproj = (const float*)d_in[4];
    const float* bproj = (const float*)d_in[5];
    const float* ln_g  = (const float*)d_in[6];
    const float* ln_b  = (const float*)d_in[7];
    const float* a1p   = (const float*)d_in[8];
    const float* a2p   = (const float*)d_in[9];
    float* out = (float*)d_out;

    char* wsb = (char*)d_ws;
    float* pooled = (float*)(wsb);                                   // 2 MB [b][n][c]
    f16* xT    = (f16*)(wsb + ((size_t)2 << 20));                    // 1 MB
    f16* wq16  = (f16*)(wsb + ((size_t)3 << 20));                    // 128 KB
    f16* wkv16 = (f16*)(wsb + ((size_t)3 << 20) + (128 << 10));      // 256 KB
    f16* wp16  = (f16*)(wsb + ((size_t)3 << 20) + (384 << 10));      // 128 KB
    f16* q16   = (f16*)(wsb + ((size_t)3 << 20) + (512 << 10));      // 1 MB
    f16* k16   = (f16*)(wsb + ((size_t)3 << 20) + (512 << 10) + ((size_t)1 << 20));
    f16* vT16  = (f16*)(wsb + ((size_t)3 << 20) + (512 << 10) + ((size_t)2 << 20));
    f16* oat   = (f16*)(wsb + ((size_t)3 << 20) + (512 << 10) + ((size_t)3 << 20));

    prep_kernel<<<1536, 256, 0, stream>>>(y, pooled, x, xT, Wq, Wkv, Wproj,
                                          wq16, wkv16, wp16);
    qkv_kernel<<<384, 256, 0, stream>>>(xT, pooled, ln_g, ln_b, wq16, wkv16,
                                        q16, k16, vT16);
    attn_kernel<<<1024, 1024, 0, stream>>>(q16, k16, vT16, a1p, a2p, oat);
    projgemm_kernel<<<128, 256, 0, stream>>>(oat, wp16, bproj, out);
}

// Round 6
// 69.109 us; speedup vs baseline: 1.1506x; 1.1506x over previous
//
#include <hip/hip_runtime.h>

typedef _Float16 f16;
typedef f16 f16x8 __attribute__((ext_vector_type(8)));
typedef f16 f16x4 __attribute__((ext_vector_type(4)));
typedef float f32x4 __attribute__((ext_vector_type(4)));

constexpr float ATT_SCALE = 0.17677669529663687f; // 1/sqrt(32)

// ---------------- DPP wave-64 reductions (no LDS, no ds_bpermute) ----------------
template<int C> __device__ __forceinline__ float dppadd(float v) {
    return v + __int_as_float(__builtin_amdgcn_update_dpp(0, __float_as_int(v), C, 0xf, 0xf, true));
}
template<int C> __device__ __forceinline__ float dppmax(float v) {
    return fmaxf(v, __int_as_float(__builtin_amdgcn_update_dpp(__float_as_int(v), __float_as_int(v), C, 0xf, 0xf, false)));
}
__device__ __forceinline__ float wave_sum(float v) {
    v = dppadd<0x111>(v); v = dppadd<0x112>(v); v = dppadd<0x114>(v); v = dppadd<0x118>(v);
    v = dppadd<0x142>(v); v = dppadd<0x143>(v);
    return __int_as_float(__builtin_amdgcn_readlane(__float_as_int(v), 63));
}
__device__ __forceinline__ float wave_max(float v) {
    v = dppmax<0x111>(v); v = dppmax<0x112>(v); v = dppmax<0x114>(v); v = dppmax<0x118>(v);
    v = dppmax<0x142>(v); v = dppmax<0x143>(v);
    return __int_as_float(__builtin_amdgcn_readlane(__float_as_int(v), 63));
}

// ------- merged prep: avg-pool (bid<512) | x transpose (bid<1024) | weight cast -------
__global__ __launch_bounds__(256) void prep_kernel(const float* __restrict__ y,
                                                   float* __restrict__ pooled,
                                                   const float* __restrict__ x,
                                                   f16* __restrict__ xT,
                                                   const float* __restrict__ Wq,
                                                   const float* __restrict__ Wkv,
                                                   const float* __restrict__ Wp,
                                                   f16* __restrict__ wq16,
                                                   f16* __restrict__ wkv16,
                                                   f16* __restrict__ wp16)
{
    __shared__ float sh[1444];
    int bid = blockIdx.x, t = threadIdx.x;
    if (bid < 512) {
        float (*p)[38] = (float(*)[38])sh;
        const float* plane = y + (size_t)bid * 1024;
        for (int i = t; i < 38 * 38; i += 256) (&p[0][0])[i] = 0.f;
        __syncthreads();
        for (int i = t; i < 1024; i += 256) p[(i >> 5) + 3][(i & 31) + 3] = plane[i];
        __syncthreads();
        int b = bid >> 8, c = bid & 255;
        for (int i = t; i < 1024; i += 256) {
            int r = (i >> 5) + 3, cc = (i & 31) + 3;
            float s3 = 0.f;
            #pragma unroll
            for (int dr = -1; dr <= 1; ++dr)
                #pragma unroll
                for (int dc = -1; dc <= 1; ++dc) s3 += p[r + dr][cc + dc];
            float r5 = 0.f;
            #pragma unroll
            for (int dc = -2; dc <= 2; ++dc) r5 += p[r - 2][cc + dc] + p[r + 2][cc + dc];
            #pragma unroll
            for (int dr = -1; dr <= 1; ++dr) r5 += p[r + dr][cc - 2] + p[r + dr][cc + 2];
            float r7 = 0.f;
            #pragma unroll
            for (int dc = -3; dc <= 3; ++dc) r7 += p[r - 3][cc + dc] + p[r + 3][cc + dc];
            #pragma unroll
            for (int dr = -2; dr <= 2; ++dr) r7 += p[r + dr][cc - 3] + p[r + dr][cc + 3];
            float s5 = s3 + r5, s7 = s5 + r7;
            pooled[((size_t)b * 1024 + i) * 256 + c] =
                s3 * (1.f / 9.f) + s5 * (1.f / 25.f) + s7 * (1.f / 49.f);
        }
    } else if (bid < 1024) {
        float (*tile)[33] = (float(*)[33])sh;
        int id = bid - 512;
        int b = id >> 8, ct = (id >> 5) & 7, nt = id & 31;
        int rr = t >> 5, j = t & 31;
        #pragma unroll
        for (int r = rr; r < 32; r += 8)
            tile[r][j] = x[((size_t)b * 256 + ct * 32 + r) * 1024 + nt * 32 + j];
        __syncthreads();
        #pragma unroll
        for (int r = rr; r < 32; r += 8)
            xT[((size_t)b * 1024 + nt * 32 + r) * 256 + ct * 32 + j] = (f16)tile[j][r];
    } else {
        int i = (bid - 1024) * 256 + t;
        if (i < 65536) { wq16[i] = (f16)Wq[i]; wp16[i] = (f16)Wp[i]; }
        wkv16[i] = (f16)Wkv[i];
    }
}

// ---------------- merged Q and KV projections (KV with fused LayerNorm) ----------------
__device__ __forceinline__ void gemm_tile(const f16* __restrict__ A, const f16* __restrict__ Bm,
                                          int row0, int ncol0, int l15, int lhi, f32x4 acc[4])
{
    for (int k0 = 0; k0 < 256; k0 += 32) {
        f16x8 a = *(const f16x8*)(A + (size_t)(row0 + l15) * 256 + k0 + lhi * 8);
        #pragma unroll
        for (int j = 0; j < 4; ++j) {
            f16x8 bf = *(const f16x8*)(Bm + (size_t)(ncol0 + j * 16 + l15) * 256 + k0 + lhi * 8);
            acc[j] = __builtin_amdgcn_mfma_f32_16x16x32_f16(a, bf, acc[j], 0, 0, 0);
        }
    }
}

__global__ __launch_bounds__(256) void qkv_kernel(const f16* __restrict__ xT,
                                                  const float* __restrict__ pooled,
                                                  const float* __restrict__ lng,
                                                  const float* __restrict__ lnb,
                                                  const f16* __restrict__ wq16,
                                                  const f16* __restrict__ wkv16,
                                                  f16* __restrict__ q16,
                                                  f16* __restrict__ k16,
                                                  f16* __restrict__ vT16)
{
    __shared__ f16 At[64 * 256];     // 32 KB swizzled A-tile (KV path only)
    int w = threadIdx.x >> 6, lane = threadIdx.x & 63;
    int l15 = lane & 15, lhi = lane >> 4;
    if (blockIdx.x < 128) {
        int mt = blockIdx.x >> 2, nt = blockIdx.x & 3;
        int row0 = mt * 64 + w * 16;
        f32x4 acc[4] = {};
        gemm_tile(xT, wq16, row0, nt * 64, l15, lhi, acc);
        #pragma unroll
        for (int j = 0; j < 4; ++j) {
            int col = nt * 64 + j * 16 + l15;
            int h = col >> 5, d = col & 31;
            #pragma unroll
            for (int r = 0; r < 4; ++r) {
                int row = row0 + 4 * lhi + r;
                int b = row >> 10, n = row & 1023;
                q16[(((size_t)(b * 8 + h)) * 1024 + n) * 32 + d] = (f16)(acc[j][r] * ATT_SCALE);
            }
        }
    } else {
        int bid = blockIdx.x - 128;
        int mt = bid >> 3, nt = bid & 7;
        int row0g = mt * 64;
        float4 gg = ((const float4*)lng)[lane];
        float4 bb = ((const float4*)lnb)[lane];
        for (int rr = 0; rr < 16; ++rr) {
            int r = w * 16 + rr;
            float4 v = *(const float4*)(pooled + (size_t)(row0g + r) * 256 + lane * 4);
            float su = v.x + v.y + v.z + v.w;
            float s2 = v.x * v.x + v.y * v.y + v.z * v.z + v.w * v.w;
            su = wave_sum(su); s2 = wave_sum(s2);
            float muv = su * (1.f / 256.f);
            float rstd = rsqrtf(s2 * (1.f / 256.f) - muv * muv + 1e-5f);
            f16x4 o;
            o[0] = (f16)((v.x - muv) * rstd * gg.x + bb.x);
            o[1] = (f16)((v.y - muv) * rstd * gg.y + bb.y);
            o[2] = (f16)((v.z - muv) * rstd * gg.z + bb.z);
            o[3] = (f16)((v.w - muv) * rstd * gg.w + bb.w);
            *(f16x4*)(At + r * 256 + ((lane * 4) ^ ((r & 7) << 3))) = o;
        }
        __syncthreads();
        f32x4 acc[4] = {};
        int a_r = w * 16 + l15;
        int asw = (a_r & 7) << 3;
        for (int k0 = 0; k0 < 256; k0 += 32) {
            f16x8 a = *(const f16x8*)(At + a_r * 256 + ((k0 + lhi * 8) ^ asw));
            #pragma unroll
            for (int j = 0; j < 4; ++j) {
                f16x8 bf = *(const f16x8*)(wkv16 + (size_t)(nt * 64 + j * 16 + l15) * 256 + k0 + lhi * 8);
                acc[j] = __builtin_amdgcn_mfma_f32_16x16x32_f16(a, bf, acc[j], 0, 0, 0);
            }
        }
        #pragma unroll
        for (int j = 0; j < 4; ++j) {
            int col = nt * 64 + j * 16 + l15;
            #pragma unroll
            for (int r = 0; r < 4; ++r) {
                int row = row0g + w * 16 + 4 * lhi + r;
                int b = row >> 10, n = row & 1023;
                float v = acc[j][r];
                if (col < 256) {
                    int h = col >> 5, d = col & 31;
                    k16[(((size_t)(b * 8 + h)) * 1024 + n) * 32 + d] = (f16)v;
                } else {
                    int c2 = col - 256, h = c2 >> 5, d = c2 & 31;
                    vT16[(((size_t)(b * 8 + h)) * 32 + d) * 1024 + n] = (f16)v;
                }
            }
        }
    }
}

// ---------------- count of s[i] >= m across the wave (ballot/popc, SALU-heavy) --------
__device__ __forceinline__ int cnt16(const float* s, float m)
{
    int c = 0;
    #pragma unroll
    for (int i = 0; i < 16; ++i)
        c += (int)__popcll(__ballot(s[i] >= m));
    return c;
}

// branchless bracket widen from probe counts
#define WIDEN(sarr, aa, bb, K, mn4, mxv, lo, hi, cl, ch) { \
    int _ca = cnt16(sarr, (aa)); int _cb = cnt16(sarr, (bb)); \
    bool _lm = _ca < (K); bool _hm = _cb > (K); \
    lo = _lm ? (mn4) : (_hm ? (bb) : (aa)); \
    hi = _lm ? (aa)  : (_hm ? (mxv) : (bb)); \
    cl = _lm ? 1024.f : (_hm ? (float)_cb : (float)_ca); \
    ch = _lm ? (float)_ca : (_hm ? 1.f : (float)_cb); }

// midpoint: alternate regula-falsi (clamped) / bisection — it is compile-time constant
#define MID(it, lo, hi, cl, ch, K, m) { \
    if ((it) & 1) { m = 0.5f * (lo + hi); } \
    else { float _den = fmaxf(cl - ch, 1.0f); \
        m = lo + (hi - lo) * (cl - (float)(K)) * __builtin_amdgcn_rcpf(_den); \
        float _mg = 0.12f * (hi - lo); \
        m = fminf(fmaxf(m, lo + _mg), hi - _mg); } }

#define UPD(cv, K, lo, hi, cl, ch, m) { bool _g = (cv) >= (K); \
    lo = _g ? (m) : lo; cl = _g ? (float)(cv) : cl; \
    hi = _g ? hi : (m); ch = _g ? ch : (float)(cv); }

// -------- fused attention v6: 8 waves, f16 LDS, reg-resident dual-row 4-way search ----
__global__ __launch_bounds__(512, 4) void attn_kernel(const f16* __restrict__ q16,
                                                      const f16* __restrict__ k16,
                                                      const f16* __restrict__ vT16,
                                                      const float* __restrict__ a1p,
                                                      const float* __restrict__ a2p,
                                                      f16* __restrict__ oat)
{
    __shared__ f16 Sb[16 * 1024];        // 32 KB, pair(8-elem)-swizzled
    int bid = blockIdx.x;
    int bh = bid >> 6, rb = bid & 63;
    int row0 = rb * 16;
    int w = threadIdx.x >> 6, lane = threadIdx.x & 63;   // w in [0,8)
    int l15 = lane & 15, lhi = lane >> 4;
    const f16* Qb = q16 + (size_t)bh * 32768;
    const f16* Kb = k16 + (size_t)bh * 32768;
    const f16* Vb = vT16 + (size_t)bh * 32768;

    // ---- phase 1: S = Q K^T (swapped mfma(K,Q)); f16 pair-swizzled stores
    {
        f16x8 qf = *(const f16x8*)(Qb + (size_t)(row0 + l15) * 32 + lhi * 8);
        int q = l15, sw1 = q & 7;
        int phalf = (lhi & 1) * 4;
        #pragma unroll
        for (int j = 0; j < 8; ++j) {
            int c0 = w * 128 + j * 16;
            f16x8 kf = *(const f16x8*)(Kb + (size_t)(c0 + l15) * 32 + lhi * 8);
            f32x4 z = {0.f, 0.f, 0.f, 0.f};
            f32x4 d = __builtin_amdgcn_mfma_f32_16x16x32_f16(kf, qf, z, 0, 0, 0);
            int pl = (c0 >> 3) + (lhi >> 1);
            int pp = pl ^ sw1;
            f16x4 hv;
            hv[0] = (f16)d[0]; hv[1] = (f16)d[1]; hv[2] = (f16)d[2]; hv[3] = (f16)d[3];
            *(f16x4*)(Sb + q * 1024 + pp * 8 + phalf) = hv;
        }
    }
    __syncthreads();

    // ---- phase 2: rows r0=2w, r1=2w+1; 4 searches interleaved, all state in regs
    float c_a1 = a1p[0], c_a2 = a2p[0];
    int r0 = 2 * w, r1 = r0 + 1;
    int cs0 = r0 & 7, cs1 = r1 & 7;
    float s0[16], s1[16];
    {
        f16x8 ha = *(const f16x8*)(Sb + r0 * 1024 + ((lane ^ cs0) << 3));
        f16x8 hb = *(const f16x8*)(Sb + r0 * 1024 + (((64 + lane) ^ cs0) << 3));
        f16x8 hc = *(const f16x8*)(Sb + r1 * 1024 + ((lane ^ cs1) << 3));
        f16x8 hd = *(const f16x8*)(Sb + r1 * 1024 + (((64 + lane) ^ cs1) << 3));
        #pragma unroll
        for (int i = 0; i < 8; ++i) {
            s0[i] = (float)ha[i]; s0[8 + i] = (float)hb[i];
            s1[i] = (float)hc[i]; s1[8 + i] = (float)hd[i];
        }
    }
    // stats
    float mx0l = s0[0], mx1l = s1[0];
    float su0 = 0.f, q0 = 0.f, su1 = 0.f, q1 = 0.f;
    #pragma unroll
    for (int i = 0; i < 16; ++i) {
        mx0l = fmaxf(mx0l, s0[i]); su0 += s0[i]; q0 = fmaf(s0[i], s0[i], q0);
        mx1l = fmaxf(mx1l, s1[i]); su1 += s1[i]; q1 = fmaf(s1[i], s1[i], q1);
    }
    float mx0 = wave_max(mx0l), mx1 = wave_max(mx1l);
    float mu0 = wave_sum(su0) * (1.f / 1024.f), mu1 = wave_sum(su1) * (1.f / 1024.f);
    float sg0 = sqrtf(fmaxf(wave_sum(q0) * (1.f / 1024.f) - mu0 * mu0, 1e-30f));
    float sg1 = sqrtf(fmaxf(wave_sum(q1) * (1.f / 1024.f) - mu1 * mu1, 1e-30f));

    // Gaussian-init brackets: z=0 for k=512, z=0.4316 for k=341
    float lo1, hi1, cl1, ch1, lo2, hi2, cl2, ch2;
    float lo3, hi3, cl3, ch3, lo4, hi4, cl4, ch4;
    {
        float d0 = 0.25f * sg0, d1 = 0.25f * sg1;
        float g0 = mu0 + 0.4316f * sg0, g1 = mu1 + 0.4316f * sg1;
        float mn40 = mu0 - 4.f * sg0, mn41 = mu1 - 4.f * sg1;
        WIDEN(s0, mu0 - d0, mu0 + d0, 512, mn40, mx0, lo1, hi1, cl1, ch1);
        WIDEN(s0, g0 - d0,  g0 + d0,  341, mn40, mx0, lo2, hi2, cl2, ch2);
        WIDEN(s1, mu1 - d1, mu1 + d1, 512, mn41, mx1, lo3, hi3, cl3, ch3);
        WIDEN(s1, g1 - d1,  g1 + d1,  341, mn41, mx1, lo4, hi4, cl4, ch4);
    }
    #pragma unroll
    for (int it = 0; it < 8; ++it) {
        float m1, m2, m3, m4;
        MID(it, lo1, hi1, cl1, ch1, 512, m1);
        MID(it, lo2, hi2, cl2, ch2, 341, m2);
        MID(it, lo3, hi3, cl3, ch3, 512, m3);
        MID(it, lo4, hi4, cl4, ch4, 341, m4);
        int c1 = cnt16(s0, m1);
        int c2 = cnt16(s0, m2);
        int c3 = cnt16(s1, m3);
        int c4 = cnt16(s1, m4);
        UPD(c1, 512, lo1, hi1, cl1, ch1, m1);
        UPD(c2, 341, lo2, hi2, cl2, ch2, m2);
        UPD(c3, 512, lo3, hi3, cl3, ch3, m3);
        UPD(c4, 341, lo4, hi4, cl4, ch4, m4);
    }
    // T = lo (count(>=lo) >= k)
    {
        float t1a[16], t2a[16];
        float l1 = 0.f, l2 = 0.f;
        #pragma unroll
        for (int i = 0; i < 16; ++i) {
            float ev = __expf(s0[i] - mx0);
            float u1 = (s0[i] >= lo1) ? ev : 0.f;
            float u2 = (s0[i] >= lo2) ? ev : 0.f;
            t1a[i] = u1; t2a[i] = u2;
            l1 += u1; l2 += u2;
        }
        l1 = wave_sum(l1); l2 = wave_sum(l2);
        float w1 = c_a1 / l1, w2 = c_a2 / l2;
        f16x8 oa, ob;
        #pragma unroll
        for (int i = 0; i < 8; ++i) {
            oa[i] = (f16)(t1a[i] * w1 + t2a[i] * w2);
            ob[i] = (f16)(t1a[8 + i] * w1 + t2a[8 + i] * w2);
        }
        *(f16x8*)(Sb + r0 * 1024 + ((lane ^ cs0) << 3)) = oa;
        *(f16x8*)(Sb + r0 * 1024 + (((64 + lane) ^ cs0) << 3)) = ob;
    }
    {
        float t1b[16], t2b[16];
        float l3 = 0.f, l4 = 0.f;
        #pragma unroll
        for (int i = 0; i < 16; ++i) {
            float ev = __expf(s1[i] - mx1);
            float u1 = (s1[i] >= lo3) ? ev : 0.f;
            float u2 = (s1[i] >= lo4) ? ev : 0.f;
            t1b[i] = u1; t2b[i] = u2;
            l3 += u1; l4 += u2;
        }
        l3 = wave_sum(l3); l4 = wave_sum(l4);
        float w3 = c_a1 / l3, w4 = c_a2 / l4;
        f16x8 oc, od;
        #pragma unroll
        for (int i = 0; i < 8; ++i) {
            oc[i] = (f16)(t1b[i] * w3 + t2b[i] * w4);
            od[i] = (f16)(t1b[8 + i] * w3 + t2b[8 + i] * w4);
        }
        *(f16x8*)(Sb + r1 * 1024 + ((lane ^ cs1) << 3)) = oc;
        *(f16x8*)(Sb + r1 * 1024 + (((64 + lane) ^ cs1) << 3)) = od;
    }
    __syncthreads();

    // ---- phase 3: out = W V; wave w covers m-range [w*128, w*128+128)
    f32x4 acc0 = {}, acc1 = {};
    #pragma unroll
    for (int ks = 0; ks < 4; ++ks) {
        int pl = w * 16 + ks * 4 + lhi;
        int pp = pl ^ (l15 & 7);
        f16x8 af = *(const f16x8*)(Sb + l15 * 1024 + (pp << 3));
        int m0 = w * 128 + ks * 32 + lhi * 8;
        f16x8 b0 = *(const f16x8*)(Vb + (size_t)l15 * 1024 + m0);
        f16x8 b1v = *(const f16x8*)(Vb + (size_t)(16 + l15) * 1024 + m0);
        acc0 = __builtin_amdgcn_mfma_f32_16x16x32_f16(af, b0, acc0, 0, 0, 0);
        acc1 = __builtin_amdgcn_mfma_f32_16x16x32_f16(af, b1v, acc1, 0, 0, 0);
    }
    __syncthreads();
    float* Pf = (float*)Sb;              // reuse LDS as 8x512 f32 partials (16 KB)
    #pragma unroll
    for (int r2 = 0; r2 < 4; ++r2) {
        int rw = 4 * lhi + r2;
        Pf[w * 512 + rw * 32 + l15]      = acc0[r2];
        Pf[w * 512 + rw * 32 + 16 + l15] = acc1[r2];
    }
    __syncthreads();
    if (threadIdx.x < 128) {
        int o4 = threadIdx.x << 2;
        float4 v = *(const float4*)&Pf[o4];
        #pragma unroll
        for (int ww = 1; ww < 8; ++ww) {
            float4 p = *(const float4*)&Pf[ww * 512 + o4];
            v.x += p.x; v.y += p.y; v.z += p.z; v.w += p.w;
        }
        int rr = o4 >> 5, d0 = o4 & 31;
        int b = bh >> 3, h = bh & 7;
        f16x4 o;
        o[0] = (f16)v.x; o[1] = (f16)v.y; o[2] = (f16)v.z; o[3] = (f16)v.w;
        *(f16x4*)(oat + ((size_t)b * 1024 + row0 + rr) * 256 + h * 32 + d0) = o;
    }
}

// ---------------- output projection + bias, LDS-transposed coalesced writes ---------
__global__ __launch_bounds__(256) void projgemm_kernel(const f16* __restrict__ A,
                                                       const f16* __restrict__ Bm,
                                                       const float* __restrict__ bias,
                                                       float* __restrict__ out)
{
    __shared__ float tile[64][65];
    int mt = blockIdx.x >> 2, nt = blockIdx.x & 3;
    int w = threadIdx.x >> 6, lane = threadIdx.x & 63;
    int l15 = lane & 15, lhi = lane >> 4;
    int row0 = mt * 64 + w * 16;
    f32x4 acc[4] = {};
    gemm_tile(A, Bm, row0, nt * 64, l15, lhi, acc);
    #pragma unroll
    for (int j = 0; j < 4; ++j) {
        int col_l = j * 16 + l15;
        float bv = bias[nt * 64 + col_l];
        #pragma unroll
        for (int r = 0; r < 4; ++r)
            tile[col_l][w * 16 + 4 * lhi + r] = acc[j][r] + bv;
    }
    __syncthreads();
    int b = (mt * 64) >> 10, n0 = (mt * 64) & 1023;
    int col_l = threadIdx.x >> 2, part = threadIdx.x & 3;
    size_t base = (size_t)b * 262144 + (size_t)(nt * 64 + col_l) * 1024 + n0 + part * 16;
    #pragma unroll
    for (int q = 0; q < 4; ++q) {
        float4 v;
        v.x = tile[col_l][part * 16 + q * 4 + 0];
        v.y = tile[col_l][part * 16 + q * 4 + 1];
        v.z = tile[col_l][part * 16 + q * 4 + 2];
        v.w = tile[col_l][part * 16 + q * 4 + 3];
        *(float4*)(out + base + q * 4) = v;
    }
}

extern "C" void kernel_launch(void* const* d_in, const int* in_sizes, int n_in,
                              void* d_out, int out_size, void* d_ws, size_t ws_size,
                              hipStream_t stream)
{
    const float* x     = (const float*)d_in[0];
    const float* y     = (const float*)d_in[1];
    const float* Wq    = (const float*)d_in[2];
    const float* Wkv   = (const float*)d_in[3];
    const float* Wproj = (const float*)d_in[4];
    const float* bproj = (const float*)d_in[5];
    const float* ln_g  = (const float*)d_in[6];
    const float* ln_b  = (const float*)d_in[7];
    const float* a1p   = (const float*)d_in[8];
    const float* a2p   = (const float*)d_in[9];
    float* out = (float*)d_out;

    char* wsb = (char*)d_ws;
    float* pooled = (float*)(wsb);                                   // 2 MB [b][n][c]
    f16* xT    = (f16*)(wsb + ((size_t)2 << 20));                    // 1 MB
    f16* wq16  = (f16*)(wsb + ((size_t)3 << 20));                    // 128 KB
    f16* wkv16 = (f16*)(wsb + ((size_t)3 << 20) + (128 << 10));      // 256 KB
    f16* wp16  = (f16*)(wsb + ((size_t)3 << 20) + (384 << 10));      // 128 KB
    f16* q16   = (f16*)(wsb + ((size_t)3 << 20) + (512 << 10));      // 1 MB
    f16* k16   = (f16*)(wsb + ((size_t)3 << 20) + (512 << 10) + ((size_t)1 << 20));
    f16* vT16  = (f16*)(wsb + ((size_t)3 << 20) + (512 << 10) + ((size_t)2 << 20));
    f16* oat   = (f16*)(wsb + ((size_t)3 << 20) + (512 << 10) + ((size_t)3 << 20));

    prep_kernel<<<1536, 256, 0, stream>>>(y, pooled, x, xT, Wq, Wkv, Wproj,
                                          wq16, wkv16, wp16);
    qkv_kernel<<<384, 256, 0, stream>>>(xT, pooled, ln_g, ln_b, wq16, wkv16,
                                        q16, k16, vT16);
    attn_kernel<<<1024, 512, 0, stream>>>(q16, k16, vT16, a1p, a2p, oat);
    projgemm_kernel<<<128, 256, 0, stream>>>(oat, wp16, bproj, out);
}